// Round 3
// baseline (187.022 us; speedup 1.0000x reference)
//
#include <hip/hip_runtime.h>

// BATCH=65536, DIM=512, NUM_CLASSES=1000, NUM_OLD=500
constexpr int kDim = 512;
constexpr int kF4PerRow = kDim / 4;  // 128 float4/row

__device__ __forceinline__ float sqdiff4(float4 e, float4 c) {
    float d, t;
    d = e.x - c.x; t  = d * d;
    d = e.y - c.y; t += d * d;
    d = e.z - c.z; t += d * d;
    d = e.w - c.w; t += d * d;
    return t;
}

// Each 64-sample chunk is serviced by a PAIR of waves; each wave of the pair
// covers 64 of the 128 float4 columns of every masked row. 2048 waves total
// at B=65536 -> 512 blocks x 4 waves = 2 blocks/CU, 8 waves/CU.
__global__ __launch_bounds__(256) void mse_masked_kernel(
    const float* __restrict__ emb,
    const float* __restrict__ cen,
    const int* __restrict__ labels,
    const int* __restrict__ num_old_p,
    int batch,
    float* __restrict__ ws_sum,
    unsigned int* __restrict__ ws_cnt)
{
    const int num_old = *num_old_p;
    const int lane = threadIdx.x & 63;
    const int wid  = threadIdx.x >> 6;
    const int wpb  = blockDim.x >> 6;
    const int gwave = blockIdx.x * wpb + wid;
    const int nwave = gridDim.x * wpb;

    const int half = gwave & 1;            // which 64-float4 half of each row
    const int col  = half * 64 + lane;     // this wave's float4 column

    const float4* __restrict__ emb4 = (const float4*)emb;
    const float4* __restrict__ cen4 = (const float4*)cen;

    float acc = 0.0f;
    unsigned int cnt = 0;

    const int nchunks = (batch + 63) >> 6;
    for (int ch = (gwave >> 1); ch < nchunks; ch += (nwave >> 1)) {
        const int chunk = ch * 64;
        const int idx = chunk + lane;
        const int mylab = (idx < batch) ? labels[idx] : 0x7fffffff;
        unsigned long long m = __ballot(mylab < num_old);
        if (half == 0) cnt += (unsigned int)__popcll(m);   // count once per pair

        // 8 rows in flight: 16 independent 16B loads per burst.
        while (__popcll(m) >= 8) {
            int b[8], l[8];
            #pragma unroll
            for (int i = 0; i < 8; ++i) { b[i] = __builtin_ctzll(m); m &= m - 1; }
            #pragma unroll
            for (int i = 0; i < 8; ++i) l[i] = __shfl(mylab, b[i], 64);

            float4 e[8], c[8];
            #pragma unroll
            for (int i = 0; i < 8; ++i)
                e[i] = emb4[(size_t)(chunk + b[i]) * kF4PerRow + col];
            #pragma unroll
            for (int i = 0; i < 8; ++i)
                c[i] = cen4[(size_t)l[i] * kF4PerRow + col];

            #pragma unroll
            for (int i = 0; i < 8; ++i)
                acc += sqdiff4(e[i], c[i]);
        }
        // Remainder rows.
        while (m) {
            const int b = __builtin_ctzll(m); m &= m - 1;
            const int l = __shfl(mylab, b, 64);
            float4 e = emb4[(size_t)(chunk + b) * kF4PerRow + col];
            float4 c = cen4[(size_t)l * kF4PerRow + col];
            acc += sqdiff4(e, c);
        }
    }

    // Wave butterfly reduce
    #pragma unroll
    for (int off = 32; off > 0; off >>= 1)
        acc += __shfl_xor(acc, off, 64);

    __shared__ float        s_sum[8];
    __shared__ unsigned int s_cnt[8];
    if (lane == 0) { s_sum[wid] = acc; s_cnt[wid] = cnt; }
    __syncthreads();

    if (threadIdx.x == 0) {
        float        bs = 0.0f;
        unsigned int bc = 0u;
        for (int i = 0; i < wpb; ++i) { bs += s_sum[i]; bc += s_cnt[i]; }
        ws_sum[blockIdx.x] = bs;
        ws_cnt[blockIdx.x] = bc;
    }
}

__global__ __launch_bounds__(256) void finalize_kernel(
    const float* __restrict__ ws_sum,
    const unsigned int* __restrict__ ws_cnt,
    int nparts,
    float* __restrict__ out)
{
    const int t = threadIdx.x;
    float        s = 0.0f;
    unsigned int c = 0u;
    for (int i = t; i < nparts; i += blockDim.x) { s += ws_sum[i]; c += ws_cnt[i]; }

    #pragma unroll
    for (int off = 32; off > 0; off >>= 1) {
        s += __shfl_xor(s, off, 64);
        c += __shfl_xor(c, off, 64);
    }
    __shared__ float        ls[4];
    __shared__ unsigned int lc[4];
    const int lane = t & 63, wid = t >> 6;
    if (lane == 0) { ls[wid] = s; lc[wid] = c; }
    __syncthreads();
    if (t == 0) {
        float        ts = ls[0] + ls[1] + ls[2] + ls[3];
        unsigned int tc = lc[0] + lc[1] + lc[2] + lc[3];
        const float total = ts * (1.0f / (float)kDim);
        out[0] = (tc == 0u) ? total : total / (float)tc;
    }
}

extern "C" void kernel_launch(void* const* d_in, const int* in_sizes, int n_in,
                              void* d_out, int out_size, void* d_ws, size_t ws_size,
                              hipStream_t stream) {
    const float* emb       = (const float*)d_in[0];  // [65536, 512] f32
    const float* cen       = (const float*)d_in[1];  // [1000, 512]  f32
    const int*   labels    = (const int*)d_in[2];    // [65536] i32
    const int*   num_old_p = (const int*)d_in[3];    // scalar i32

    const int batch = in_sizes[2];

    const int blocks = 512;  // 2048 waves = 1024 chunks x wave-pair
    float*        ws_sum = (float*)d_ws;
    unsigned int* ws_cnt = (unsigned int*)((char*)d_ws + blocks * sizeof(float));

    mse_masked_kernel<<<blocks, 256, 0, stream>>>(emb, cen, labels, num_old_p,
                                                  batch, ws_sum, ws_cnt);
    finalize_kernel<<<1, 256, 0, stream>>>(ws_sum, ws_cnt, blocks, (float*)d_out);
}